// Round 1
// baseline (871.101 us; speedup 1.0000x reference)
//
#include <hip/hip_runtime.h>
#include <stdint.h>
#include <math.h>

// ---------------------------------------------------------------------------
// MultiScaleResidualQuantizer3D  (B=128, C=32, HW=16, N_E=4096, 10 scales)
// Round 0: correct fp32 implementation.
//   - scoring: fp32 VALU dot vs normalized codebook (token norm skipped: argmax
//     invariant under positive row scaling)
//   - cross-block argmax via packed u64 atomicMax, first-index tie-break
//   - f_rest never materialized (== f_input - f_hat)
//   - PHI_IDX resolved by exact double arithmetic of np.linspace ties:
//     [0,0,0,1,1,2,2,2,3,3]   (si=2 and si=7 are exact fp ties -> first index)
// ---------------------------------------------------------------------------

#define DEVI __device__ __forceinline__

static constexpr int NE = 4096;

DEVI unsigned fkey(float f) {
    unsigned u = __float_as_uint(f);
    return (u & 0x80000000u) ? ~u : (u | 0x80000000u);  // order-preserving
}
DEVI unsigned long long packSI(float s, int idx) {
    // high: monotone score key; low: ~idx so ties prefer SMALLER idx (first max)
    return ((unsigned long long)fkey(s) << 32) | (unsigned)(~(unsigned)idx);
}
DEVI int unpackI(unsigned long long v) {
    return (int)(~(unsigned)(v & 0xFFFFFFFFull));
}

// --------------------------- setup kernels ---------------------------------

// normalized codebook rows: cbn[r] = cb[r] / max(||cb[r]||, 1e-12)
__global__ void __launch_bounds__(256) k_cbn(const float* __restrict__ cb,
                                             float* __restrict__ cbn) {
    int r = blockIdx.x * 256 + threadIdx.x;
    if (r >= NE) return;
    const float* src = cb + r * 32;
    float v[32];
    float ss = 0.f;
#pragma unroll
    for (int j = 0; j < 32; ++j) { v[j] = src[j]; ss += v[j] * v[j]; }
    float n = fmaxf(sqrtf(ss), 1e-12f);
#pragma unroll
    for (int j = 0; j < 32; ++j) cbn[r * 32 + j] = v[j] / n;
}

// wT[k][(ic*9+ky*3+kx)][oc] = phi_w[k][oc][ic][ky][kx]  (oc-contiguous for
// wave-uniform scalar weight loads in conv).  Block 144 computes bicubic U
// matrices (float64 math matching numpy, accumulate into float32).
__global__ void __launch_bounds__(256) k_setupB(const float* __restrict__ pw,
                                                float* __restrict__ wT,
                                                float* __restrict__ um) {
    int blk = blockIdx.x;
    if (blk < 144) {
        int e = blk * 256 + threadIdx.x;            // < 36864
        int k = e / 9216, rem = e % 9216;
        int s = rem / 32, oc = rem % 32;
        int ic = s / 9, k9 = s % 9, ky = k9 / 3, kx = k9 % 3;
        wT[e] = pw[(((k * 32 + oc) * 32 + ic) * 3 + ky) * 3 + kx];
    } else {
        int t = threadIdx.x;
        if (t >= 144) return;
        const int pns[9] = {1, 2, 3, 4, 5, 6, 8, 10, 13};
        int si = t / 16, y = t % 16, pn = pns[si];
        double scale = (double)pn / 16.0;
        double src = ((double)y + 0.5) * scale - 0.5;
        double fl = floor(src);
        int i0 = (int)fl;
        double f = src - fl;
        float row[13];
        for (int j = 0; j < pn; ++j) row[j] = 0.f;
        const double a = -0.75;
#pragma unroll
        for (int off = -1; off <= 2; ++off) {
            double t2 = fabs(f - (double)off);
            double wgt;
            if (t2 <= 1.0)      wgt = ((a + 2.0) * t2 - (a + 3.0)) * t2 * t2 + 1.0;
            else if (t2 < 2.0)  wgt = (((t2 - 5.0) * t2 + 8.0) * t2 - 4.0) * a;
            else                wgt = 0.0;
            int j = i0 + off;
            j = j < 0 ? 0 : (j > pn - 1 ? pn - 1 : j);
            row[j] = (float)((double)row[j] + wgt);   // numpy f32 += f64
        }
        for (int j = 0; j < pn; ++j) um[si * 256 + y * pn + j] = row[j];
    }
}

// ----------------------- per-scale kernels ---------------------------------

// area downsample of (f_input - f_hat) -> xtok[c*T + t]; also zeroes best[t]
template <int PN>
__global__ void __launch_bounds__(256) k_down(const float* __restrict__ fin,
                                              const float* __restrict__ fhat,
                                              float* __restrict__ xtok,
                                              unsigned long long* __restrict__ best) {
    constexpr int T = 128 * PN * PN;
    int id = blockIdx.x * 256 + threadIdx.x;
    if (id < T) best[id] = 0ull;
    if (id >= 32 * T) return;
    int c = id / T, t = id % T;
    int b = t / (PN * PN), r = t % (PN * PN), oy = r / PN, ox = r % PN;
    int sy = oy * 16 / PN, ey = ((oy + 1) * 16 + PN - 1) / PN;
    int sx = ox * 16 / PN, ex = ((ox + 1) * 16 + PN - 1) / PN;
    float wy = (float)(1.0 / (double)(ey - sy));
    float wx = (float)(1.0 / (double)(ex - sx));
    const float* pi = fin + b * 8192 + c * 256;
    const float* ph = fhat + b * 8192 + c * 256;
    float s = 0.f;
    for (int y = sy; y < ey; ++y)
        for (int x = sx; x < ex; ++x)
            s += pi[y * 16 + x] - ph[y * 16 + x];
    xtok[id] = s * (wy * wx);
}

// cosine argmax: 512 tokens/block (2 per thread), code segment per block,
// codebook chunk staged in LDS (broadcast reads), result merged via atomicMax.
template <int PN, int SEG, bool DIRECT>
__global__ void __launch_bounds__(256) k_quant(const float* __restrict__ xa,
                                               const float* __restrict__ xb,
                                               const float* __restrict__ cbn,
                                               unsigned long long* __restrict__ best) {
    constexpr int T = 128 * PN * PN;
    constexpr int NBT = (T + 511) / 512;
    constexpr int CPS = 4096 / SEG;                 // codes per segment
    constexpr int CHUNK = (CPS < 128) ? CPS : 128;  // codes staged at once
    __shared__ __align__(16) float cb[CHUNK * 32];
    int bt = blockIdx.x % NBT, seg = blockIdx.x / NBT;
    int tid = threadIdx.x;
    int t0 = bt * 512 + tid, t1 = t0 + 256;
    bool v0 = t0 < T, v1 = t1 < T;
    float x0[32], x1[32];
#pragma unroll
    for (int j = 0; j < 32; ++j) { x0[j] = 0.f; x1[j] = 0.f; }
    if (DIRECT) {  // last scale: residual read straight from f_input - f_hat
        if (v0) {
            int b = t0 >> 8, p = t0 & 255;
#pragma unroll
            for (int j = 0; j < 32; ++j)
                x0[j] = xa[b * 8192 + j * 256 + p] - xb[b * 8192 + j * 256 + p];
        }
        if (v1) {
            int b = t1 >> 8, p = t1 & 255;
#pragma unroll
            for (int j = 0; j < 32; ++j)
                x1[j] = xa[b * 8192 + j * 256 + p] - xb[b * 8192 + j * 256 + p];
        }
    } else {
        if (v0) {
#pragma unroll
            for (int j = 0; j < 32; ++j) x0[j] = xa[j * T + t0];
        }
        if (v1) {
#pragma unroll
            for (int j = 0; j < 32; ++j) x1[j] = xa[j * T + t1];
        }
    }
    float m0 = -3.4e38f, m1 = -3.4e38f;
    int i0 = 0, i1 = 0;
    int cbase = seg * CPS;
    for (int cc0 = 0; cc0 < CPS; cc0 += CHUNK) {
        const float4* src = (const float4*)(cbn + (cbase + cc0) * 32);
        for (int i = tid; i < CHUNK * 8; i += 256) ((float4*)cb)[i] = src[i];
        __syncthreads();
        for (int cc = 0; cc < CHUNK; ++cc) {
            const float4* cr = (const float4*)(cb + cc * 32);
            float a0 = 0, a1 = 0, a2 = 0, a3 = 0, b0 = 0, b1 = 0, b2 = 0, b3 = 0;
#pragma unroll
            for (int j = 0; j < 8; ++j) {
                float4 c4 = cr[j];  // wave-uniform address -> LDS broadcast
                a0 = fmaf(x0[4 * j + 0], c4.x, a0);
                a1 = fmaf(x0[4 * j + 1], c4.y, a1);
                a2 = fmaf(x0[4 * j + 2], c4.z, a2);
                a3 = fmaf(x0[4 * j + 3], c4.w, a3);
                b0 = fmaf(x1[4 * j + 0], c4.x, b0);
                b1 = fmaf(x1[4 * j + 1], c4.y, b1);
                b2 = fmaf(x1[4 * j + 2], c4.z, b2);
                b3 = fmaf(x1[4 * j + 3], c4.w, b3);
            }
            float s0 = (a0 + a1) + (a2 + a3);
            float s1 = (b0 + b1) + (b2 + b3);
            int code = cbase + cc0 + cc;
            if (s0 > m0) { m0 = s0; i0 = code; }
            if (s1 > m1) { m1 = s1; i1 = code; }
        }
        __syncthreads();
    }
    if (v0) atomicMax(best + t0, packSI(m0, i0));
    if (v1) atomicMax(best + t1, packSI(m1, i1));
}

// gather codes -> bicubic upsample -> 3x3 conv (phi) -> f_hat update + loss.
// grid 256 = (image, half); threads 256 = (128 px, 2 ic-halves).
template <int PN, int K, bool LAST>
__global__ void __launch_bounds__(256) k_conv(const float* __restrict__ fin,
                                              float* __restrict__ fhat,
                                              const float* __restrict__ cbook,
                                              const unsigned long long* __restrict__ best,
                                              const float* __restrict__ wT,
                                              const float* __restrict__ phib,
                                              const float* __restrict__ um,
                                              float* __restrict__ lossAcc,
                                              float* __restrict__ dout) {
    constexpr int NR = 9;        // rows staged: half (8) + halo (1, edge-clipped)
    constexpr int NT = PN * PN;  // tokens per image
    __shared__ float h0[NT * 32];                      // [token][c]
    __shared__ float hu[32 * NR * 18];                 // [c][ry][x+1], padded cols
    __shared__ float hu1[(PN < 16) ? 32 * NR * PN : 1];
    __shared__ float Us[(PN < 16) ? 16 * PN : 1];
    __shared__ int idxs[256];
    __shared__ float partial[128 * 33];                // +1 pad: no bank conflict
    __shared__ float red[256];

    int b = blockIdx.x >> 1, half = blockIdx.x & 1;
    int y0 = half * 8, ylo = half ? 7 : 0;
    int tid = threadIdx.x;

    if (tid < NT) idxs[tid] = unpackI(best[b * NT + tid]);
    if (PN < 16)
        for (int e = tid; e < 16 * PN; e += 256) Us[e] = um[e];
    __syncthreads();

    for (int e = tid; e < NT * 32; e += 256) {
        int tk = e >> 5, c = e & 31;
        h0[e] = cbook[idxs[tk] * 32 + c];
    }
    __syncthreads();

    if (PN < 16) {
        // rows:  hu1[c][ry][i] = sum_j U[yy][j] * h0[j*PN+i][c]   (lanes vary c)
        for (int e = tid; e < NR * PN * 32; e += 256) {
            int ryi = e >> 5, c = e & 31;
            int ry = ryi / PN, i = ryi % PN;
            int yy = ylo + ry;
            float s = 0.f;
            for (int j = 0; j < PN; ++j) s += Us[yy * PN + j] * h0[(j * PN + i) * 32 + c];
            hu1[(c * NR + ry) * PN + i] = s;
        }
        __syncthreads();
        // cols:  hu[c][ry][x+1] = sum_i U[x][i] * hu1[c][ry][i]   (lanes vary x)
        for (int e = tid; e < 32 * NR * 16; e += 256) {
            int cr = e >> 4, x = e & 15;
            int c = cr / NR, ry = cr % NR;
            float s = 0.f;
            for (int i = 0; i < PN; ++i) s += Us[x * PN + i] * hu1[(c * NR + ry) * PN + i];
            hu[(c * NR + ry) * 18 + x + 1] = s;
        }
    } else {
        for (int e = tid; e < 32 * NR * 16; e += 256) {
            int c = e & 31, q = e >> 5;
            int ry = q / 16, xx = q & 15;
            hu[(c * NR + ry) * 18 + xx + 1] = h0[((ylo + ry) * 16 + xx) * 32 + c];
        }
    }
    for (int e = tid; e < 32 * NR; e += 256) {  // zero-pad columns
        hu[e * 18 + 0] = 0.f;
        hu[e * 18 + 17] = 0.f;
    }
    __syncthreads();

    // conv: thread = (pixel, ic-half); all 32 oc accumulated in registers;
    // weights via wave-uniform index -> scalar loads (separate SMEM pipe).
    int px = tid & 127, ich = tid >> 7;
    int row = px >> 4, y = y0 + row, x = px & 15;
    float acc[32];
#pragma unroll
    for (int o = 0; o < 32; ++o) acc[o] = 0.f;
    const float* wk = wT + K * 9216;
    for (int ii = 0; ii < 16; ++ii) {
        int ic = ich * 16 + ii;
#pragma unroll
        for (int ky = 0; ky < 3; ++ky) {
            int gy = y + ky - 1;
            if (gy < 0 || gy > 15) continue;  // zero padding rows
            int ry = gy - ylo;
            const float* hrow = hu + (ic * NR + ry) * 18 + x;  // window x..x+2
            float hv0 = hrow[0], hv1 = hrow[1], hv2 = hrow[2];
            int sb = __builtin_amdgcn_readfirstlane(ic * 9 + ky * 3) * 32;
            const float* w0 = wk + sb;
#pragma unroll
            for (int o = 0; o < 32; ++o) {
                acc[o] = fmaf(w0[o],      hv0, acc[o]);
                acc[o] = fmaf(w0[32 + o], hv1, acc[o]);
                acc[o] = fmaf(w0[64 + o], hv2, acc[o]);
            }
        }
    }
    if (ich == 1) {
#pragma unroll
        for (int o = 0; o < 32; ++o) partial[px * 33 + o] = acc[o];
    }
    __syncthreads();

    float ss = 0.f;
    if (ich == 0) {
        const float* bias = phib + K * 32;
        int g = b * 8192 + y * 16 + x;
        int ryc = y - ylo;
#pragma unroll
        for (int o = 0; o < 32; ++o) {
            float conv = acc[o] + partial[px * 33 + o] + bias[o];
            float hval = 0.5f * hu[(o * NR + ryc) * 18 + x + 1] + 0.5f * conv;
            float fh = fhat[g + o * 256] + hval;
            fhat[g + o * 256] = fh;
            if (LAST) dout[g + o * 256] = fh;
            float d = fh - fin[g + o * 256];
            ss = fmaf(d, d, ss);
        }
    }
    red[tid] = ss;
    __syncthreads();
    for (int s = 128; s > 0; s >>= 1) {
        if (tid < s) red[tid] += red[tid + s];
        __syncthreads();
    }
    if (tid == 0) atomicAdd(lossAcc, red[0]);
}

__global__ void __launch_bounds__(256) k_hist(const unsigned long long* __restrict__ best,
                                              int* __restrict__ hist) {
    int t = blockIdx.x * 256 + threadIdx.x;
    if (t >= 32768) return;
    atomicAdd(hist + unpackI(best[t]), 1);
}

__global__ void __launch_bounds__(256) k_final(const float* __restrict__ lossAcc,
                                               const int* __restrict__ hist,
                                               float* __restrict__ out) {
    __shared__ float red[256];
    int tid = threadIdx.x;
    float s = 0.f;
    for (int i = tid; i < 4096; i += 256) {
        float p = (float)hist[i] * (1.f / 32768.f);
        s += p * logf(p + 1e-10f);
    }
    red[tid] = s;
    __syncthreads();
    for (int k = 128; k > 0; k >>= 1) {
        if (tid < k) red[tid] += red[tid + k];
        __syncthreads();
    }
    if (tid == 0) {
        out[1048577] = expf(-red[0]);
        float L = 0.f;
        for (int si = 0; si < 10; ++si) L += lossAcc[si];
        out[1048576] = L * 1.25f / 1048576.f * 0.1f;
    }
}

// ------------------------------ launch -------------------------------------

extern "C" void kernel_launch(void* const* d_in, const int* in_sizes, int n_in,
                              void* d_out, int out_size, void* d_ws, size_t ws_size,
                              hipStream_t stream) {
    const float* f_in  = (const float*)d_in[0];   // [128,32,16,16]
    const float* cbook = (const float*)d_in[1];   // [4096,32]
    const float* phiw  = (const float*)d_in[2];   // [4,32,32,3,3]
    const float* phib  = (const float*)d_in[3];   // [4,32]
    float* out = (float*)d_out;
    float* w = (float*)d_ws;

    // workspace layout (float offsets)
    float* fhat    = w;                                   // 1048576
    float* lossAcc = w + 1048576;                         // 16
    int*   hist    = (int*)(w + 1048592);                 // 4096
    float* cbn     = w + 1052688;                         // 131072
    float* wT      = w + 1183760;                         // 36864
    float* um      = w + 1220624;                         // 9*256
    float* xtok    = w + 1222928;                         // 32*21632 max
    unsigned long long* best = (unsigned long long*)(w + 1915152);  // 32768 u64

    hipMemsetAsync(fhat, 0, (1048576 + 16 + 4096) * sizeof(float), stream);
    k_cbn<<<16, 256, 0, stream>>>(cbook, cbn);
    k_setupB<<<145, 256, 0, stream>>>(phiw, wT, um);

#define SCALE(SI, PN, SEG, K)                                                          \
    {                                                                                  \
        constexpr int T = 128 * PN * PN;                                               \
        k_down<PN><<<T / 8, 256, 0, stream>>>(f_in, fhat, xtok, best);                 \
        k_quant<PN, SEG, false><<<((T + 511) / 512) * SEG, 256, 0, stream>>>(          \
            xtok, xtok, cbn, best);                                                    \
        k_conv<PN, K, false><<<256, 256, 0, stream>>>(f_in, fhat, cbook, best, wT,     \
                                                      phib, um + SI * 256,             \
                                                      lossAcc + SI, out);              \
    }
    SCALE(0, 1, 64, 0);
    SCALE(1, 2, 64, 0);
    SCALE(2, 3, 64, 0);
    SCALE(3, 4, 64, 1);
    SCALE(4, 5, 64, 1);
    SCALE(5, 6, 64, 2);
    SCALE(6, 8, 64, 2);
    SCALE(7, 10, 32, 2);
    SCALE(8, 13, 16, 3);
#undef SCALE

    {  // last scale (pn=16): direct residual read, histogram for perplexity
        constexpr int T = 128 * 256;
        hipMemsetAsync(best, 0, T * sizeof(unsigned long long), stream);
        k_quant<16, 16, true><<<(T / 512) * 16, 256, 0, stream>>>(f_in, fhat, cbn, best);
        k_hist<<<128, 256, 0, stream>>>(best, hist);
        k_conv<16, 3, true><<<256, 256, 0, stream>>>(f_in, fhat, cbook, best, wT, phib,
                                                     um, lossAcc + 9, out);
    }
    k_final<<<1, 256, 0, stream>>>(lossAcc, hist, out);
}

// Round 2
// 786.877 us; speedup vs baseline: 1.1070x; 1.1070x over previous
//
#include <hip/hip_runtime.h>
#include <stdint.h>
#include <math.h>

// ---------------------------------------------------------------------------
// MultiScaleResidualQuantizer3D  (B=128, C=32, HW=16, N_E=4096, 10 scales)
// Round 1: MFMA fp16 3-term split scoring (xh*ch + xl*ch + xh*cl), fp32 acc.
//   - dropped term xl*cl ~ 2^-24 relative: below fp32-reassociation noise
//   - wave = 128 tokens (8 M-tiles), codebook segment staged in LDS
//     (stride 40 halfs = 80B rows: ds_read_b128 bank-conflict-free-ish)
//   - argmax: per-lane cmp/sel in regs, 16-lane xor-shuffle merge on packed
//     u64 (fkey(score)<<32 | ~idx), atomicMax across code segments
//   - PHI_IDX = [0,0,0,1,1,2,2,2,3,3] (exact np.linspace tie resolution)
// ---------------------------------------------------------------------------

#define DEVI __device__ __forceinline__

static constexpr int NE = 4096;

typedef _Float16 half8 __attribute__((ext_vector_type(8)));
typedef float floatx4 __attribute__((ext_vector_type(4)));

DEVI unsigned fkey(float f) {
    unsigned u = __float_as_uint(f);
    return (u & 0x80000000u) ? ~u : (u | 0x80000000u);  // order-preserving
}
DEVI unsigned long long packSI(float s, unsigned idx) {
    // high: monotone score key; low: ~idx so ties prefer SMALLER idx (first max)
    return ((unsigned long long)fkey(s) << 32) | (unsigned)(~idx);
}
DEVI int unpackI(unsigned long long v) {
    return (int)(~(unsigned)(v & 0xFFFFFFFFull));
}
DEVI unsigned long long shflx(unsigned long long v, int m) {
    // xor-shuffle by mask m (<16): two 32-bit shuffles
    unsigned lo = (unsigned)v, hi = (unsigned)(v >> 32);
    lo = __shfl_xor(lo, m, 64);
    hi = __shfl_xor(hi, m, 64);
    return ((unsigned long long)hi << 32) | lo;
}

// --------------------------- setup kernels ---------------------------------

// normalized codebook rows split to fp16 hi/lo: v = hi + lo + O(2^-24)
__global__ void __launch_bounds__(256) k_cbn(const float* __restrict__ cb,
                                             _Float16* __restrict__ cbh,
                                             _Float16* __restrict__ cbl) {
    int r = blockIdx.x * 256 + threadIdx.x;
    if (r >= NE) return;
    const float* src = cb + r * 32;
    float v[32];
    float ss = 0.f;
#pragma unroll
    for (int j = 0; j < 32; ++j) { v[j] = src[j]; ss += v[j] * v[j]; }
    float n = fmaxf(sqrtf(ss), 1e-12f);
#pragma unroll
    for (int j = 0; j < 32; ++j) {
        float x = v[j] / n;
        _Float16 h = (_Float16)x;
        cbh[r * 32 + j] = h;
        cbl[r * 32 + j] = (_Float16)(x - (float)h);
    }
}

// wT[k][(ic*9+ky*3+kx)][oc] = phi_w[k][oc][ic][ky][kx]; block 144: bicubic U
__global__ void __launch_bounds__(256) k_setupB(const float* __restrict__ pw,
                                                float* __restrict__ wT,
                                                float* __restrict__ um) {
    int blk = blockIdx.x;
    if (blk < 144) {
        int e = blk * 256 + threadIdx.x;            // < 36864
        int k = e / 9216, rem = e % 9216;
        int s = rem / 32, oc = rem % 32;
        int ic = s / 9, k9 = s % 9, ky = k9 / 3, kx = k9 % 3;
        wT[e] = pw[(((k * 32 + oc) * 32 + ic) * 3 + ky) * 3 + kx];
    } else {
        int t = threadIdx.x;
        if (t >= 144) return;
        const int pns[9] = {1, 2, 3, 4, 5, 6, 8, 10, 13};
        int si = t / 16, y = t % 16, pn = pns[si];
        double scale = (double)pn / 16.0;
        double src = ((double)y + 0.5) * scale - 0.5;
        double fl = floor(src);
        int i0 = (int)fl;
        double f = src - fl;
        float row[13];
        for (int j = 0; j < pn; ++j) row[j] = 0.f;
        const double a = -0.75;
#pragma unroll
        for (int off = -1; off <= 2; ++off) {
            double t2 = fabs(f - (double)off);
            double wgt;
            if (t2 <= 1.0)      wgt = ((a + 2.0) * t2 - (a + 3.0)) * t2 * t2 + 1.0;
            else if (t2 < 2.0)  wgt = (((t2 - 5.0) * t2 + 8.0) * t2 - 4.0) * a;
            else                wgt = 0.0;
            int j = i0 + off;
            j = j < 0 ? 0 : (j > pn - 1 ? pn - 1 : j);
            row[j] = (float)((double)row[j] + wgt);   // numpy f32 += f64
        }
        for (int j = 0; j < pn; ++j) um[si * 256 + y * pn + j] = row[j];
    }
}

// ----------------------- per-scale kernels ---------------------------------

// area downsample of (f_input - f_hat) -> token-major fp16 hi/lo [t*32+c];
// pads tokens T..Tp with zeros; zeroes best[0..Tp)
template <int PN>
__global__ void __launch_bounds__(256) k_down(const float* __restrict__ fin,
                                              const float* __restrict__ fhat,
                                              _Float16* __restrict__ xh,
                                              _Float16* __restrict__ xl,
                                              unsigned long long* __restrict__ best) {
    constexpr int T = 128 * PN * PN;
    constexpr int Tp = ((T + 511) / 512) * 512;
    int id = blockIdx.x * 256 + threadIdx.x;
    if (id < Tp) best[id] = 0ull;
    if (id >= 32 * Tp) return;
    int t = id >> 5, c = id & 31;
    if (t >= T) { xh[id] = (_Float16)0.f; xl[id] = (_Float16)0.f; return; }
    int b = t / (PN * PN), r = t % (PN * PN), oy = r / PN, ox = r % PN;
    int sy = oy * 16 / PN, ey = ((oy + 1) * 16 + PN - 1) / PN;
    int sx = ox * 16 / PN, ex = ((ox + 1) * 16 + PN - 1) / PN;
    float wy = 1.f / (float)(ey - sy);
    float wx = 1.f / (float)(ex - sx);
    const float* pi = fin + b * 8192 + c * 256;
    const float* ph = fhat + b * 8192 + c * 256;
    float s = 0.f;
    for (int y = sy; y < ey; ++y)
        for (int x = sx; x < ex; ++x)
            s += pi[y * 16 + x] - ph[y * 16 + x];
    float v = s * (wy * wx);
    _Float16 h = (_Float16)v;
    xh[id] = h;
    xl[id] = (_Float16)(v - (float)h);
}

// MFMA cosine argmax. Block = 4 waves; wave = 128 tokens (8 M-tiles).
// Codes split into SEG segments across blocks; chunk of CH codes staged in LDS.
template <int PN, int SEG>
__global__ void __launch_bounds__(256, 2) k_quant(
        const half8* __restrict__ xh, const half8* __restrict__ xl,
        const float4* __restrict__ cbh4, const float4* __restrict__ cbl4,
        unsigned long long* __restrict__ best) {
    constexpr int T = 128 * PN * PN;
    constexpr int Tp = ((T + 511) / 512) * 512;
    constexpr int TB = Tp / 512;
    constexpr int CPS = 4096 / SEG;                 // codes per segment
    constexpr int CH = (CPS < 128) ? CPS : 128;     // codes staged per chunk
    __shared__ __align__(16) _Float16 sh[CH * 40];  // stride 40 halfs (80B)
    __shared__ __align__(16) _Float16 sl[CH * 40];

    int tid = threadIdx.x;
    int bt = blockIdx.x % TB, seg = blockIdx.x / TB;
    int wv = tid >> 6, lane = tid & 63;
    int n0 = lane & 15, g = lane >> 4;
    int tokbase = bt * 512 + wv * 128;

    // A-fragments (tokens) resident: lane holds token tokbase+mt*16+n0, k=g*8..g*8+7
    half8 ah[8], al[8];
#pragma unroll
    for (int mt = 0; mt < 8; ++mt) {
        int tok = tokbase + mt * 16 + n0;
        ah[mt] = xh[tok * 4 + g];
        al[mt] = xl[tok * 4 + g];
    }

    float mx[8][4];
    unsigned ib[8][4];
#pragma unroll
    for (int mt = 0; mt < 8; ++mt)
#pragma unroll
        for (int r = 0; r < 4; ++r) { mx[mt][r] = -3.0e38f; ib[mt][r] = 0u; }

    const floatx4 z4 = {0.f, 0.f, 0.f, 0.f};
    int cbase = seg * CPS;
    for (int cc0 = 0; cc0 < CPS; cc0 += CH) {
        __syncthreads();
        for (int e = tid; e < CH * 4; e += 256) {   // stage chunk (hi+lo)
            int code = e >> 2, q = e & 3;
            *(float4*)(sh + code * 40 + q * 8) = cbh4[(cbase + cc0 + code) * 4 + q];
            *(float4*)(sl + code * 40 + q * 8) = cbl4[(cbase + cc0 + code) * 4 + q];
        }
        __syncthreads();
#pragma unroll 2
        for (int nt = 0; nt < CH / 16; ++nt) {
            half8 bh = *(const half8*)(sh + (nt * 16 + n0) * 40 + g * 8);
            half8 bl = *(const half8*)(sl + (nt * 16 + n0) * 40 + g * 8);
            unsigned colb = (unsigned)(cbase + cc0 + nt * 16);
#pragma unroll
            for (int mt = 0; mt < 8; ++mt) {
                floatx4 c;
                c = __builtin_amdgcn_mfma_f32_16x16x32_f16(ah[mt], bh, z4, 0, 0, 0);
                c = __builtin_amdgcn_mfma_f32_16x16x32_f16(al[mt], bh, c,  0, 0, 0);
                c = __builtin_amdgcn_mfma_f32_16x16x32_f16(ah[mt], bl, c,  0, 0, 0);
#pragma unroll
                for (int r = 0; r < 4; ++r) {
                    bool gt = c[r] > mx[mt][r];
                    mx[mt][r] = gt ? c[r] : mx[mt][r];
                    ib[mt][r] = gt ? colb : ib[mt][r];
                }
            }
        }
    }

    // merge 16 columns per token (lanes n0=0..15 within each g-group)
#pragma unroll
    for (int mt = 0; mt < 8; ++mt) {
#pragma unroll
        for (int r = 0; r < 4; ++r) {
            unsigned long long k = packSI(mx[mt][r], ib[mt][r] + (unsigned)n0);
            unsigned long long o;
            o = shflx(k, 1); k = (o > k) ? o : k;
            o = shflx(k, 2); k = (o > k) ? o : k;
            o = shflx(k, 4); k = (o > k) ? o : k;
            o = shflx(k, 8); k = (o > k) ? o : k;
            if (n0 == 0)
                atomicMax(best + (tokbase + mt * 16 + g * 4 + r), k);
        }
    }
}

// gather codes -> bicubic upsample -> 3x3 conv (phi) -> f_hat update + loss.
// grid 256 = (image, half); threads 256 = (128 px, 2 ic-halves).
template <int PN, int K, bool LAST>
__global__ void __launch_bounds__(256) k_conv(const float* __restrict__ fin,
                                              float* __restrict__ fhat,
                                              const float* __restrict__ cbook,
                                              const unsigned long long* __restrict__ best,
                                              const float* __restrict__ wT,
                                              const float* __restrict__ phib,
                                              const float* __restrict__ um,
                                              float* __restrict__ lossAcc,
                                              float* __restrict__ dout) {
    constexpr int NR = 9;        // rows staged: half (8) + halo (1, edge-clipped)
    constexpr int NT = PN * PN;  // tokens per image
    __shared__ float h0[NT * 32];                      // [token][c]
    __shared__ float hu[32 * NR * 18];                 // [c][ry][x+1], padded cols
    __shared__ float hu1[(PN < 16) ? 32 * NR * PN : 1];
    __shared__ float Us[(PN < 16) ? 16 * PN : 1];
    __shared__ int idxs[256];
    __shared__ float partial[128 * 33];                // +1 pad: no bank conflict
    __shared__ float red[256];

    int b = blockIdx.x >> 1, half = blockIdx.x & 1;
    int y0 = half * 8, ylo = half ? 7 : 0;
    int tid = threadIdx.x;

    if (tid < NT) idxs[tid] = unpackI(best[b * NT + tid]);
    if (PN < 16)
        for (int e = tid; e < 16 * PN; e += 256) Us[e] = um[e];
    __syncthreads();

    for (int e = tid; e < NT * 32; e += 256) {
        int tk = e >> 5, c = e & 31;
        h0[e] = cbook[idxs[tk] * 32 + c];
    }
    __syncthreads();

    if (PN < 16) {
        for (int e = tid; e < NR * PN * 32; e += 256) {
            int ryi = e >> 5, c = e & 31;
            int ry = ryi / PN, i = ryi % PN;
            int yy = ylo + ry;
            float s = 0.f;
            for (int j = 0; j < PN; ++j) s += Us[yy * PN + j] * h0[(j * PN + i) * 32 + c];
            hu1[(c * NR + ry) * PN + i] = s;
        }
        __syncthreads();
        for (int e = tid; e < 32 * NR * 16; e += 256) {
            int cr = e >> 4, x = e & 15;
            int c = cr / NR, ry = cr % NR;
            float s = 0.f;
            for (int i = 0; i < PN; ++i) s += Us[x * PN + i] * hu1[(c * NR + ry) * PN + i];
            hu[(c * NR + ry) * 18 + x + 1] = s;
        }
    } else {
        for (int e = tid; e < 32 * NR * 16; e += 256) {
            int c = e & 31, q = e >> 5;
            int ry = q / 16, xx = q & 15;
            hu[(c * NR + ry) * 18 + xx + 1] = h0[((ylo + ry) * 16 + xx) * 32 + c];
        }
    }
    for (int e = tid; e < 32 * NR; e += 256) {  // zero-pad columns
        hu[e * 18 + 0] = 0.f;
        hu[e * 18 + 17] = 0.f;
    }
    __syncthreads();

    int px = tid & 127, ich = tid >> 7;
    int row = px >> 4, y = y0 + row, x = px & 15;
    float acc[32];
#pragma unroll
    for (int o = 0; o < 32; ++o) acc[o] = 0.f;
    const float* wk = wT + K * 9216;
    for (int ii = 0; ii < 16; ++ii) {
        int ic = ich * 16 + ii;
#pragma unroll
        for (int ky = 0; ky < 3; ++ky) {
            int gy = y + ky - 1;
            if (gy < 0 || gy > 15) continue;  // zero padding rows
            int ry = gy - ylo;
            const float* hrow = hu + (ic * NR + ry) * 18 + x;  // window x..x+2
            float hv0 = hrow[0], hv1 = hrow[1], hv2 = hrow[2];
            int sb = __builtin_amdgcn_readfirstlane(ic * 9 + ky * 3) * 32;
            const float* w0 = wk + sb;
#pragma unroll
            for (int o = 0; o < 32; ++o) {
                acc[o] = fmaf(w0[o],      hv0, acc[o]);
                acc[o] = fmaf(w0[32 + o], hv1, acc[o]);
                acc[o] = fmaf(w0[64 + o], hv2, acc[o]);
            }
        }
    }
    if (ich == 1) {
#pragma unroll
        for (int o = 0; o < 32; ++o) partial[px * 33 + o] = acc[o];
    }
    __syncthreads();

    float ss = 0.f;
    if (ich == 0) {
        const float* bias = phib + K * 32;
        int gidx = b * 8192 + y * 16 + x;
        int ryc = y - ylo;
#pragma unroll
        for (int o = 0; o < 32; ++o) {
            float conv = acc[o] + partial[px * 33 + o] + bias[o];
            float hval = 0.5f * hu[(o * NR + ryc) * 18 + x + 1] + 0.5f * conv;
            float fh = fhat[gidx + o * 256] + hval;
            fhat[gidx + o * 256] = fh;
            if (LAST) dout[gidx + o * 256] = fh;
            float d = fh - fin[gidx + o * 256];
            ss = fmaf(d, d, ss);
        }
    }
    red[tid] = ss;
    __syncthreads();
    for (int s = 128; s > 0; s >>= 1) {
        if (tid < s) red[tid] += red[tid + s];
        __syncthreads();
    }
    if (tid == 0) atomicAdd(lossAcc, red[0]);
}

__global__ void __launch_bounds__(256) k_hist(const unsigned long long* __restrict__ best,
                                              int* __restrict__ hist) {
    int t = blockIdx.x * 256 + threadIdx.x;
    if (t >= 32768) return;
    atomicAdd(hist + unpackI(best[t]), 1);
}

__global__ void __launch_bounds__(256) k_final(const float* __restrict__ lossAcc,
                                               const int* __restrict__ hist,
                                               float* __restrict__ out) {
    __shared__ float red[256];
    int tid = threadIdx.x;
    float s = 0.f;
    for (int i = tid; i < 4096; i += 256) {
        float p = (float)hist[i] * (1.f / 32768.f);
        s += p * logf(p + 1e-10f);
    }
    red[tid] = s;
    __syncthreads();
    for (int k = 128; k > 0; k >>= 1) {
        if (tid < k) red[tid] += red[tid + k];
        __syncthreads();
    }
    if (tid == 0) {
        out[1048577] = expf(-red[0]);
        float L = 0.f;
        for (int si = 0; si < 10; ++si) L += lossAcc[si];
        out[1048576] = L * 1.25f / 1048576.f * 0.1f;
    }
}

// ------------------------------ launch -------------------------------------

extern "C" void kernel_launch(void* const* d_in, const int* in_sizes, int n_in,
                              void* d_out, int out_size, void* d_ws, size_t ws_size,
                              hipStream_t stream) {
    const float* f_in  = (const float*)d_in[0];   // [128,32,16,16]
    const float* cbook = (const float*)d_in[1];   // [4096,32]
    const float* phiw  = (const float*)d_in[2];   // [4,32,32,3,3]
    const float* phib  = (const float*)d_in[3];   // [4,32]
    float* out = (float*)d_out;
    char* base = (char*)d_ws;

    // workspace layout (bytes, all 16B-aligned)
    float* fhat    = (float*)(base);                       // 4,194,304 B
    float* lossAcc = (float*)(base + 4194304);             // 64 B
    int*   hist    = (int*)  (base + 4194368);             // 16,384 B
    float* wT      = (float*)(base + 4210752);             // 147,456 B
    float* um      = (float*)(base + 4358208);             // 9,216 B
    _Float16* cbh  = (_Float16*)(base + 4367424);          // 262,144 B
    _Float16* cbl  = (_Float16*)(base + 4629568);          // 262,144 B
    _Float16* xh   = (_Float16*)(base + 4891712);          // 2,097,152 B (Tp_max*32)
    _Float16* xl   = (_Float16*)(base + 6988864);          // 2,097,152 B
    unsigned long long* best = (unsigned long long*)(base + 9086016);  // 262,144 B

    hipMemsetAsync(fhat, 0, 4210752, stream);  // fhat + lossAcc + hist
    k_cbn<<<16, 256, 0, stream>>>(cbook, cbh, cbl);
    k_setupB<<<145, 256, 0, stream>>>(phiw, wT, um);

#define SCALE(SI, PN, SEG, K, LAST)                                                    \
    {                                                                                  \
        constexpr int T = 128 * PN * PN;                                               \
        constexpr int Tp = ((T + 511) / 512) * 512;                                    \
        constexpr int TB = Tp / 512;                                                   \
        k_down<PN><<<(Tp * 32) / 256, 256, 0, stream>>>(f_in, fhat, xh, xl, best);     \
        k_quant<PN, SEG><<<TB * SEG, 256, 0, stream>>>(                                \
            (const half8*)xh, (const half8*)xl, (const float4*)cbh,                    \
            (const float4*)cbl, best);                                                 \
        k_conv<PN, K, LAST><<<256, 256, 0, stream>>>(f_in, fhat, cbook, best, wT,      \
                                                     phib, um + SI * 256,              \
                                                     lossAcc + SI, out);               \
    }
    SCALE(0, 1, 64, 0, false);
    SCALE(1, 2, 64, 0, false);
    SCALE(2, 3, 32, 0, false);
    SCALE(3, 4, 32, 1, false);
    SCALE(4, 5, 16, 1, false);
    SCALE(5, 6, 16, 2, false);
    SCALE(6, 8, 8, 2, false);
    SCALE(7, 10, 8, 2, false);
    // pn=13 then pn=16 (last): hist between quant and conv for pn=16
    SCALE(8, 13, 4, 3, false);
    {
        constexpr int PN = 16;
        constexpr int T = 128 * PN * PN;      // 32768, Tp == T
        constexpr int TB = T / 512;           // 64
        k_down<PN><<<(T * 32) / 256, 256, 0, stream>>>(f_in, fhat, xh, xl, best);
        k_quant<PN, 4><<<TB * 4, 256, 0, stream>>>(
            (const half8*)xh, (const half8*)xl, (const float4*)cbh,
            (const float4*)cbl, best);
        k_hist<<<128, 256, 0, stream>>>(best, hist);
        k_conv<PN, 3, true><<<256, 256, 0, stream>>>(f_in, fhat, cbook, best, wT, phib,
                                                     um, lossAcc + 9, out);
    }
#undef SCALE
    k_final<<<1, 256, 0, stream>>>(lossAcc, hist, out);
}